// Round 6
// baseline (701.763 us; speedup 1.0000x reference)
//
#include <hip/hip_runtime.h>
#include <math.h>

#define HH 128
#define WW 128
#define NIMG 4
#define PP 11
#define KSIM 16
#define STRIDE_S 3
#define VRAD 32
#define WINW 65             // 2V+1
#define HREF 40
#define WREF 40
#define NPOS 118            // H-P+1
#define NGROUP (NIMG*HREF*WREF) // 6400
#define EPS_E 30.25f        // n*alpha^2*sigma^2
#define DE_C 151.25f        // D+E
#define INFD 3.0e38f

#define FOOT 84             // tile footprint (84x84): 9 + 65 + 10
#define FPITCH 85
#define SPITCH 88
#define IPITCH 100          // bm img tile pitch (pad: reads reach col 90)
#define PD2 388             // D2 pitch: 96*4+4
#define DBATCH 96
#define PADW 72             // padded dc-row width (65 -> 72, mult of 8)
#define PADDD (WINW*PADW)   // 4680
#define NBATCH 49           // ceil(4680/96)
#define CNP 120             // cnorm row pitch

// ---------------------------------------------------------------------------
// Stage 0: candidate-patch squared norms, cnorm(n,rr,cc) = sum_{11x11} img^2.
// Ref-independent -> computed once (was recomputed per reference before).
// ---------------------------------------------------------------------------
__global__ __launch_bounds__(128)
void bm_norm(const float* __restrict__ y, float* __restrict__ cnorm)
{
    int n = blockIdx.x / NPOS, rr = blockIdx.x % NPOS;
    int cc = threadIdx.x;
    if (cc < NPOS) {
        const float* img = y + n * HH * WW;
        float s = 0.f;
        for (int a = 0; a < PP; a++) {
            const float* rp = &img[(rr + a) * WW + cc];
#pragma unroll
            for (int b = 0; b < PP; b++) s += rp[b] * rp[b];
        }
        cnorm[n * NPOS * CNP + rr * CNP + cc] = s;
    }
}

// ---------------------------------------------------------------------------
// Stage 1: block matching, shared-product tiling. Block = 4x4 refs.
// Per displacement: product rows D(x,v) shared by all 16 refs (2.7x fewer
// ops than per-ref), 8-wide dc register sliding window (10x fewer LDS reads).
// Selection: per-(ref,lane) sorted top-16 in static registers, shfl merge.
// ---------------------------------------------------------------------------
__global__ __launch_bounds__(256, 2)
void bm_kernel(const float* __restrict__ y, const float* __restrict__ cnorm,
               int* __restrict__ inds)
{
    __shared__ float timg[FOOT][IPITCH];   // 33.6 KB (zero-padded)
    __shared__ float D2[20][PD2];          // 31.0 KB

    const int blk = blockIdx.x;
    const int n  = blk / 100;
    const int tr = blk % 100;
    const int ti = tr / 10, tj = tr % 10;
    const int r0 = 12 * ti - VRAD, c0 = 12 * tj - VRAD;
    const int tid = threadIdx.x;
    const float* img = y + n * HH * WW;
    const float* cn  = cnorm + n * NPOS * CNP;

    // load zero-padded 84x84 img tile (pitch 100; cols>=84 are zero pad)
    for (int t = tid; t < FOOT * IPITCH; t += 256) {
        int r = t / IPITCH, c = t % IPITCH;
        int gr = r0 + r, gc = c0 + c;
        float v = 0.f;
        if (c < FOOT && gr >= 0 && gr < HH && gc >= 0 && gc < WW)
            v = img[gr * WW + gc];
        timg[r][c] = v;
    }
    __syncthreads();

    // selection state: sorted ascending top-16 (static register indexing)
    float sv[16]; int si[16];
#pragma unroll
    for (int q = 0; q < 16; q++) { sv[q] = INFD; si[q] = 0; }

    const int prow1 = tid / 12;        // 0..19 product row   (phase 1, tid<240)
    const int dcc   = tid % 12;        // dc-chunk of 8
    const int refq  = tid >> 4;        // phase 2: ref id (u,v)
    const int dl    = tid & 15;        //          d-lane
    const int u = refq >> 2, v = refq & 3;
    const int hr = 3 * (4 * ti + u), wr = 3 * (4 * tj + v);

#pragma unroll 1
    for (int b = 0; b < NBATCH; b++) {
        // ---- phase 1: D(x, v) for 96 padded disps (8 per thread) ----
        if (tid < 240) {
            int ddp0 = b * DBATCH + dcc * 8;
            if (ddp0 < PADDD) {
                int dr   = ddp0 / PADW - VRAD;
                int dcx0 = ddp0 % PADW;        // tile col base = 32+dc0 = dcx0
                const float* row1 = &timg[(VRAD + prow1)][VRAD];
                const float* row2 = &timg[(VRAD + prow1 + dr)][dcx0];
                float a1[20], a2[27];
#pragma unroll
                for (int q = 0; q < 5; q++) {
                    float4 x4 = ((const float4*)row1)[q];
                    a1[4*q] = x4.x; a1[4*q+1] = x4.y; a1[4*q+2] = x4.z; a1[4*q+3] = x4.w;
                }
#pragma unroll
                for (int q = 0; q < 27; q++) a2[q] = row2[q];
#pragma unroll
                for (int k = 0; k < 8; k++) {
                    float d0 = 0.f, d1 = 0.f, d2 = 0.f, d3 = 0.f;
#pragma unroll
                    for (int bb = 0; bb < PP; bb++) {
                        d0 += a1[bb]     * a2[bb + k];
                        d1 += a1[3 + bb] * a2[3 + bb + k];
                        d2 += a1[6 + bb] * a2[6 + bb + k];
                        d3 += a1[9 + bb] * a2[9 + bb + k];
                    }
                    *(float4*)&D2[prow1][(dcc * 8 + k) * 4] = make_float4(d0, d1, d2, d3);
                }
            }
        }
        __syncthreads();
        // ---- phase 2: dists + sorted insertion (6 disps per thread) ----
#pragma unroll
        for (int kk = 0; kk < 6; kk++) {
            int d = dl + 16 * kk;
            int ddp = b * DBATCH + d;
            if (ddp < PADDD) {
                int dcx = ddp % PADW;
                if (dcx < WINW) {
                    int dr = ddp / PADW - VRAD, dc = dcx - VRAD;
                    int rr = hr + dr, cc = wr + dc;
                    if (rr >= 0 && rr <= HH - PP && cc >= 0 && cc <= WW - PP) {
                        float dot = 0.f;
#pragma unroll
                        for (int a = 0; a < PP; a++)
                            dot += D2[3 * u + a][d * 4 + v];
                        float val = cn[rr * CNP + cc] - 2.f * dot;
                        if (dr == 0 && dc == 0) val = -INFD;  // ref always kept
                        if (val < sv[15]) {
                            sv[15] = val; si[15] = ddp;
#pragma unroll
                            for (int q = 15; q > 0; q--) {
                                if (sv[q] < sv[q - 1]) {
                                    float tv = sv[q]; sv[q] = sv[q-1]; sv[q-1] = tv;
                                    int   tq = si[q]; si[q] = si[q-1]; si[q-1] = tq;
                                }
                            }
                        }
                    }
                }
            }
        }
        __syncthreads();
    }

    // ---- merge the 16 per-lane states of each ref (shfl-only) ----
    const int gref = n * (HREF * WREF) + (ti * 4 + u) * WREF + (tj * 4 + v);
#pragma unroll 1
    for (int sel = 0; sel < KSIM; sel++) {
        float bv = sv[0]; int bi = si[0]; int bl = dl;
#pragma unroll
        for (int m = 1; m < 16; m <<= 1) {
            float ov = __shfl_xor(bv, m, 16);
            int   oi = __shfl_xor(bi, m, 16);
            int   ol = __shfl_xor(bl, m, 16);
            if (ov < bv || (ov == bv && ol < bl)) { bv = ov; bi = oi; bl = ol; }
        }
        if (dl == 0) {
            int dr = bi / PADW - VRAD, dc = bi % PADW - VRAD;
            inds[gref * KSIM + sel] = (hr + dr) * NPOS + (wr + dc);
        }
        if (dl == bl) {   // pop head (static shift)
#pragma unroll
            for (int q = 0; q < 15; q++) { sv[q] = sv[q + 1]; si[q] = si[q + 1]; }
            sv[15] = INFD;
        }
    }
}

// ---------------------------------------------------------------------------
// Stage 2+3: tiled denoise. LDS cut to 78.7KB (acc in two 42-row half
// passes, xhat recomputed per half) -> 2 blocks/CU, all 400 co-resident.
// ---------------------------------------------------------------------------
__global__ __launch_bounds__(512, 4)
void dn_kernel(const float* __restrict__ y, const int* __restrict__ inds,
               float2* __restrict__ nd, int R)
{
    __shared__ float  src[FOOT][SPITCH];     // 29.6 KB
    __shared__ float2 accH[42][FPITCH];      // 28.6 KB (half footprint)
    __shared__ float  Qm[16][16][17];        // 17.4 KB (Q -> Qinv -> theta)
    __shared__ float  s1[16][16];
    __shared__ float  s2[16];
    __shared__ float  wl[16][16];
    __shared__ short  pr_[16][16], pc_[16][16];

    const int blk = blockIdx.x;
    const int n  = blk / 100;
    const int tr = blk % 100;
    const int ti = tr / 10, tj = tr % 10;
    const int r0 = 12 * ti - VRAD, c0 = 12 * tj - VRAD;
    const int tid = threadIdx.x;
    const float* img = y + n * HH * WW;

    if (tid < 256) {
        int g = tid >> 4, m = tid & 15;
        int gg = n * (HREF * WREF) + (ti * 4 + (g >> 2)) * WREF + (tj * 4 + (g & 3));
        int idx = inds[gg * KSIM + m];
        pr_[g][m] = (short)(idx / NPOS);
        pc_[g][m] = (short)(idx % NPOS);
    }
    for (int t = tid; t < FOOT * FOOT; t += 512) {
        int rr = t / FOOT, cc = t % FOOT;
        int gr = r0 + rr, gc = c0 + cc;
        float vv = 0.f;
        if (gr >= 0 && gr < HH && gc >= 0 && gc < WW) vv = img[gr * WW + gc];
        src[rr][cc] = vv;
    }
    __syncthreads();

    // ---- Q: 16 groups x 136 triangle entries ----
    for (int k = 0; k < 5; k++) {
        int task = tid + k * 512;
        if (task < 16 * 136) {
            int g = task / 136, e = task % 136;
            int i = (int)((sqrtf(8.f * (float)e + 1.f) - 1.f) * 0.5f + 1e-4f);
            int j = e - i * (i + 1) / 2;
            int ari = pr_[g][i] - r0, aci = pc_[g][i] - c0;
            int arj = pr_[g][j] - r0, acj = pc_[g][j] - c0;
            float s = (i == j) ? EPS_E : 0.f;
            for (int a = 0; a < PP; a++) {
                const float* Ri = &src[ari + a][aci];
                const float* Rj = &src[arj + a][acj];
#pragma unroll
                for (int b = 0; b < PP; b++) s += Ri[b] * Rj[b];
            }
            Qm[g][i][j] = s;
            Qm[g][j][i] = s;
        }
    }
    __syncthreads();

    // ---- lockstep Gauss-Jordan inversion (16 SPD matrices) ----
    const int uu = tid >> 8, ii = (tid >> 4) & 15, jj = tid & 15;
    for (int ks = 0; ks < 16; ks++) {
        float fA[8], rk[8], pv[8], aij[8];
#pragma unroll
        for (int k = 0; k < 8; k++) {
            int g = uu + 2 * k;
            fA[k]  = Qm[g][ii][ks];
            rk[k]  = Qm[g][ks][jj];
            pv[k]  = Qm[g][ks][ks];
            aij[k] = Qm[g][ii][jj];
        }
        __syncthreads();
#pragma unroll
        for (int k = 0; k < 8; k++) {
            int g = uu + 2 * k;
            float inv = 1.f / pv[k];
            float nv;
            if (ii == ks) nv = (jj == ks) ? inv : rk[k] * inv;
            else          nv = (jj == ks) ? -fA[k] * inv : aij[k] - fA[k] * rk[k] * inv;
            Qm[g][ii][jj] = nv;
        }
        __syncthreads();
    }

    // ---- s1, s2, theta (in-place), weights ----
    if (tid < 256) {
        int g = tid >> 4, a = tid & 15;
        float s = 0.f;
#pragma unroll
        for (int b2 = 0; b2 < 16; b2++) s += Qm[g][a][b2];
        s1[g][a] = s;
    }
    __syncthreads();
    if (tid < 16) {
        float s = 0.f;
#pragma unroll
        for (int a = 0; a < 16; a++) s += s1[tid][a];
        s2[tid] = s;
    }
    __syncthreads();
#pragma unroll
    for (int k = 0; k < 8; k++) {
        int g = uu + 2 * k;
        float t = ((ii == jj) ? 1.f : 0.f)
                - (Qm[g][ii][jj] - s1[g][ii] * s1[g][jj] / s2[g]) * DE_C;
        Qm[g][ii][jj] = t;
    }
    __syncthreads();
    if (tid < 256) {
        int g = tid >> 4, r = tid & 15;
        float s = 0.f;
#pragma unroll
        for (int m2 = 0; m2 < 16; m2++) { float t = Qm[g][m2][r]; s += t * t; }
        s = fminf(fmaxf(s, 1.f / 16.f), 1.f);
        wl[g][r] = 1.f / s;
    }
    __syncthreads();

    // ---- two half-passes: xhat + LDS scatter into 42-row acc, flush ----
    float2* ndI = nd + ((size_t)(blk & (R - 1)) * NIMG + n) * HH * WW;
#pragma unroll 1
    for (int half = 0; half < 2; half++) {
        const int h0 = half * 42;
        for (int t = tid; t < 42 * FPITCH; t += 512)
            accH[t / FPITCH][t % FPITCH] = make_float2(0.f, 0.f);
        __syncthreads();

        for (int it = 0; it < 2; it++) {
            int task = tid + it * 512;
            if (task < 16 * 61) {
                int g = task / 61, s = task % 61;
                int pxa = 2 * s;
                bool okB = (pxa + 1 < 121);
                int dra = pxa / 11, dca = pxa % 11;
                int drb = dra, dcb = dca + 1;
                if (dcb == 11) { drb = dra + 1; dcb = 0; }
                if (!okB) { drb = dra; dcb = dca; }

                int baseS[16];
#pragma unroll
                for (int m = 0; m < 16; m++)
                    baseS[m] = ((int)pr_[g][m] - r0) * SPITCH + ((int)pc_[g][m] - c0);

                const float* sf = &src[0][0];
                float xhA[16], xhB[16];
#pragma unroll
                for (int r = 0; r < 16; r++) { xhA[r] = 0.f; xhB[r] = 0.f; }
                const int offA = dra * SPITCH + dca, offB = drb * SPITCH + dcb;
#pragma unroll
                for (int m = 0; m < 16; m++) {
                    float yvA = sf[baseS[m] + offA];
                    float yvB = sf[baseS[m] + offB];
#pragma unroll
                    for (int r = 0; r < 16; r++) {
                        float t = Qm[g][m][r];
                        xhA[r] += t * yvA;
                        xhB[r] += t * yvB;
                    }
                }
#pragma unroll
                for (int r = 0; r < 16; r++) {
                    float wv2 = wl[g][r];
                    int ar = (int)pr_[g][r] - r0, ac = (int)pc_[g][r] - c0;
                    int hA = ar + dra;
                    if (hA >= h0 && hA < h0 + 42) {
                        float* cA = (float*)&accH[hA - h0][ac + dca];
                        __hip_atomic_fetch_add(cA,     wv2 * xhA[r],
                            __ATOMIC_RELAXED, __HIP_MEMORY_SCOPE_WORKGROUP);
                        __hip_atomic_fetch_add(cA + 1, wv2,
                            __ATOMIC_RELAXED, __HIP_MEMORY_SCOPE_WORKGROUP);
                    }
                    int hB = ar + drb;
                    if (okB && hB >= h0 && hB < h0 + 42) {
                        float* cB = (float*)&accH[hB - h0][ac + dcb];
                        __hip_atomic_fetch_add(cB,     wv2 * xhB[r],
                            __ATOMIC_RELAXED, __HIP_MEMORY_SCOPE_WORKGROUP);
                        __hip_atomic_fetch_add(cB + 1, wv2,
                            __ATOMIC_RELAXED, __HIP_MEMORY_SCOPE_WORKGROUP);
                    }
                }
            }
        }
        __syncthreads();

        for (int t = tid; t < 42 * FOOT; t += 512) {
            int rr = t / FOOT, cc = t % FOOT;
            float2 vv = accH[rr][cc];
            if (vv.y != 0.f) {
                int px = (r0 + h0 + rr) * WW + (c0 + cc);
#if defined(__has_builtin) && __has_builtin(__builtin_amdgcn_global_atomic_fadd_v2f32)
                typedef float v2f __attribute__((ext_vector_type(2)));
                __builtin_amdgcn_global_atomic_fadd_v2f32((v2f*)&ndI[px], (v2f){vv.x, vv.y});
#else
                atomicAdd(&ndI[px].x, vv.x);
                atomicAdd(&ndI[px].y, vv.y);
#endif
            }
        }
        __syncthreads();
    }
}

// ---------------------------------------------------------------------------
// Stage 4: out = sum_r num_r / sum_r den_r
// ---------------------------------------------------------------------------
__global__ __launch_bounds__(256)
void fin_kernel(const float2* __restrict__ nd, float* __restrict__ out, int R)
{
    int t = blockIdx.x * 256 + threadIdx.x;
    if (t < NIMG * HH * WW) {
        float sn = 0.f, sd = 0.f;
        for (int r = 0; r < R; r++) {
            float2 vv = nd[(size_t)r * NIMG * HH * WW + t];
            sn += vv.x; sd += vv.y;
        }
        out[t] = sn / sd;
    }
}

extern "C" void kernel_launch(void* const* d_in, const int* in_sizes, int n_in,
                              void* d_out, int out_size, void* d_ws, size_t ws_size,
                              hipStream_t stream)
{
    const float* y = (const float*)d_in[0];
    float* out = (float*)d_out;

    size_t perRep = (size_t)NIMG * HH * WW * sizeof(float2);   // 524288
    size_t indsB  = (size_t)NGROUP * KSIM * sizeof(int);       // 409600
    size_t cnormB = (size_t)NIMG * NPOS * CNP * sizeof(float); // 226560
    int R = 1;
    while (R < 4 && perRep * (size_t)(R * 2) + indsB + cnormB <= ws_size) R <<= 1;

    float2* nd    = (float2*)d_ws;
    int*    inds  = (int*)((char*)d_ws + perRep * (size_t)R);
    float*  cnorm = (float*)((char*)inds + indsB);

    hipMemsetAsync(nd, 0, perRep * (size_t)R, stream);
    bm_norm<<<NIMG * NPOS, 128, 0, stream>>>(y, cnorm);
    bm_kernel<<<NIMG * 100, 256, 0, stream>>>(y, cnorm, inds);
    dn_kernel<<<NIMG * 100, 512, 0, stream>>>(y, inds, nd, R);
    fin_kernel<<<(NIMG * HH * WW + 255) / 256, 256, 0, stream>>>(nd, out, R);
}